// Round 3
// baseline (997.484 us; speedup 1.0000x reference)
//
#include <hip/hip_runtime.h>
#include <hip/hip_bf16.h>
#include <math.h>

// ---------------------------------------------------------------------------
// Problem constants
// ---------------------------------------------------------------------------
#define B_SZ 8
#define L_SZ 1024
#define DM 512          // d_model
#define DFF 2048        // d_ff
#define DIN 1024        // expand * d_model
#define DSTATE 16
#define DTRANK 32
#define MROWS (B_SZ * L_SZ)   // 8192

typedef __hip_bfloat16 bf16;
typedef unsigned short u16;
using f32x4 = __attribute__((ext_vector_type(4))) float;
using bfrag = __attribute__((ext_vector_type(8))) short;   // 8 bf16 = 4 VGPR

__device__ inline float ldf(const float* p, long i) { return p[i]; }
__device__ inline float ldf(const bf16* p, long i) {
  return __uint_as_float((unsigned)((const u16*)p)[i] << 16);
}
__device__ inline void stf(float* p, long i, float v) { p[i] = v; }
__device__ inline void stf(bf16* p, long i, float v) { p[i] = __float2bfloat16(v); }
__device__ inline float b2f(u16 x) {
  return __uint_as_float((unsigned)x << 16);
}
__device__ inline u16 f2b(float v) {
  union { bf16 h; u16 u; } c;
  c.h = __float2bfloat16(v);
  return c.u;
}

// Raw v_exp_f32: computes 2^x in one trans-pipe instruction.
__device__ inline float fexp2(float x) {
  float r;
  asm("v_exp_f32 %0, %1" : "=v"(r) : "v"(x));
  return r;
}

// B-element loader (4 consecutive): fp32 direct, bf16 convert.
__device__ inline float4 ld4f_bt(const float* p) { return *(const float4*)p; }
__device__ inline float4 ld4f_bt(const bf16* p) {
  ushort4 u = *(const ushort4*)p;
  float4 v;
  v.x = b2f(u.x); v.y = b2f(u.y); v.z = b2f(u.z); v.w = b2f(u.w);
  return v;
}

// 16-element row loader into packed bf16 (2 x uint4). bf16 src: direct.
// fp32 src: inline RNE convert (matches cvt path numerically).
__device__ inline void ld16(const bf16* p, uint4& lo, uint4& hi) {
  lo = *(const uint4*)p;
  hi = *(const uint4*)((const u16*)p + 8);
}
__device__ inline void ld16(const float* p, uint4& lo, uint4& hi) {
  float4 a = *(const float4*)p, b = *(const float4*)(p + 4);
  float4 c = *(const float4*)(p + 8), d = *(const float4*)(p + 12);
  union { uint4 v; u16 s[8]; } L, H;
  L.s[0] = f2b(a.x); L.s[1] = f2b(a.y); L.s[2] = f2b(a.z); L.s[3] = f2b(a.w);
  L.s[4] = f2b(b.x); L.s[5] = f2b(b.y); L.s[6] = f2b(b.z); L.s[7] = f2b(b.w);
  H.s[0] = f2b(c.x); H.s[1] = f2b(c.y); H.s[2] = f2b(c.z); H.s[3] = f2b(c.w);
  H.s[4] = f2b(d.x); H.s[5] = f2b(d.y); H.s[6] = f2b(d.z); H.s[7] = f2b(d.w);
  lo = L.v; hi = H.v;
}

// DPP rotation-butterfly add within a 16-lane row: pure VALU, no LGKM waits.
template <int CTRL>
__device__ inline float dpp_ror_add(float x) {
  int r = __builtin_amdgcn_update_dpp(0, __float_as_int(x), CTRL, 0xf, 0xf, true);
  return x + __int_as_float(r);
}
__device__ inline float row16_sum(float x) {
  x = dpp_ror_add<0x128>(x);  // row_ror:8
  x = dpp_ror_add<0x124>(x);  // row_ror:4
  x = dpp_ror_add<0x122>(x);  // row_ror:2
  x = dpp_ror_add<0x121>(x);  // row_ror:1
  return x;
}

// ---------------------------------------------------------------------------
// fp32 -> bf16 convert (weights -> d_out scratch)
// ---------------------------------------------------------------------------
__global__ __launch_bounds__(256) void cvt_k(const float* __restrict__ s,
                                             bf16* __restrict__ d, int n) {
  int i = blockIdx.x * 256 + threadIdx.x;
  if (i < n) d[i] = __float2bfloat16(s[i]);
}

// ---------------------------------------------------------------------------
// bf16 MFMA GEMM: C(M,N) = A(M,K) @ W(N,K)^T, fp32 accumulate.
// 128x128 tile, BK=32, 4 waves, each 64x64 via 4x4 v_mfma_f32_16x16x32_bf16.
// TA may be float (inline bf16 conversion in staging). W always bf16.
// ---------------------------------------------------------------------------
constexpr int MEPI_STORE_BF16 = 0;
constexpr int MEPI_GATE = 1;        // C[oi] = C[oi] * silu(acc), bf16 in-place
constexpr int MEPI_BIAS_GELU = 2;   // bf16 out
constexpr int MEPI_BIAS_RES = 3;    // fp32 out = acc + bias + res

template <int EPI, bool FLIPA, typename TA, typename TO>
__global__ __launch_bounds__(256) void mgemm_k(
    const TA* __restrict__ Ab, int lda,
    const bf16* __restrict__ Wb, int ldw,
    TO* __restrict__ C, int ldc,
    const float* __restrict__ bias,
    const float* __restrict__ res,
    int K) {
  __shared__ u16 Asm[128][40];
  __shared__ u16 Wsm[128][40];
  const int tid = threadIdx.x;
  const int m0 = blockIdx.y * 128;
  const int n0 = blockIdx.x * 128;

  const int srow = tid >> 1;
  const int scol = (tid & 1) * 16;
  int ar = m0 + srow;
  if (FLIPA) { int t = ar & (L_SZ - 1); ar = (ar - t) + (L_SZ - 1 - t); }
  const TA* Ag = Ab + (long)ar * lda + scol;
  const u16* Wg = (const u16*)Wb + (long)(n0 + srow) * ldw + scol;

  const int lane = tid & 63, quad = lane >> 4, l16 = lane & 15;
  const int wid = tid >> 6;
  const int wm = (wid & 1) * 64, wn = (wid >> 1) * 64;

  f32x4 acc[4][4];
#pragma unroll
  for (int i = 0; i < 4; ++i)
#pragma unroll
    for (int j = 0; j < 4; ++j) acc[i][j] = {0.f, 0.f, 0.f, 0.f};

  for (int k0 = 0; k0 < K; k0 += 32) {
    uint4 av0, av1, wv0, wv1;
    ld16(Ag + k0, av0, av1);
    ld16((const bf16*)(Wg + k0), wv0, wv1);
    __syncthreads();
    *(uint4*)&Asm[srow][scol] = av0;
    *(uint4*)&Asm[srow][scol + 8] = av1;
    *(uint4*)&Wsm[srow][scol] = wv0;
    *(uint4*)&Wsm[srow][scol + 8] = wv1;
    __syncthreads();
    bfrag a[4], b[4];
#pragma unroll
    for (int mi = 0; mi < 4; ++mi)
      a[mi] = *(const bfrag*)&Asm[wm + mi * 16 + l16][quad * 8];
#pragma unroll
    for (int ni = 0; ni < 4; ++ni)
      b[ni] = *(const bfrag*)&Wsm[wn + ni * 16 + l16][quad * 8];
#pragma unroll
    for (int mi = 0; mi < 4; ++mi)
#pragma unroll
      for (int ni = 0; ni < 4; ++ni)
        acc[mi][ni] = __builtin_amdgcn_mfma_f32_16x16x32_bf16(
            a[mi], b[ni], acc[mi][ni], 0, 0, 0);
  }

#pragma unroll
  for (int mi = 0; mi < 4; ++mi)
#pragma unroll
    for (int ni = 0; ni < 4; ++ni)
#pragma unroll
      for (int r = 0; r < 4; ++r) {
        int row = m0 + wm + mi * 16 + quad * 4 + r;
        int col = n0 + wn + ni * 16 + l16;
        long oi = (long)row * ldc + col;
        float v = acc[mi][ni][r];
        if (EPI == MEPI_STORE_BF16) {
          stf(C, oi, v);
        } else if (EPI == MEPI_GATE) {
          float y = ldf((const bf16*)C, oi);
          float sz = v / (1.f + __expf(-v));
          stf(C, oi, y * sz);
        } else if (EPI == MEPI_BIAS_GELU) {
          v += bias[col];
          v = 0.5f * v * (1.f + erff(v * 0.70710678118654752440f));
          stf(C, oi, v);
        } else if (EPI == MEPI_BIAS_RES) {
          ((float*)C)[oi] = v + bias[col] + res[oi];
        }
      }
}

// ---------------------------------------------------------------------------
// MFMA merge: newx(M,DM) = y1 @ W1^T + flip_L(y2) @ W2^T + xres (fp32 out).
// ---------------------------------------------------------------------------
__global__ __launch_bounds__(256) void mmerge_k(
    const bf16* __restrict__ y1, const bf16* __restrict__ y2,
    const bf16* __restrict__ W1, const bf16* __restrict__ W2,
    const float* __restrict__ xres, float* __restrict__ newx) {
  __shared__ u16 Asm[128][40];
  __shared__ u16 Wsm[128][40];
  const int tid = threadIdx.x;
  const int m0 = blockIdx.y * 128;
  const int n0 = blockIdx.x * 128;

  const int srow = tid >> 1;
  const int scol = (tid & 1) * 16;
  int r1 = m0 + srow;
  int tt = r1 & (L_SZ - 1);
  int r2 = (r1 - tt) + (L_SZ - 1 - tt);
  const u16* A1g = (const u16*)y1 + (long)r1 * DIN + scol;
  const u16* A2g = (const u16*)y2 + (long)r2 * DIN + scol;
  const u16* W1g = (const u16*)W1 + (long)(n0 + srow) * DIN + scol;
  const u16* W2g = (const u16*)W2 + (long)(n0 + srow) * DIN + scol;

  const int lane = tid & 63, quad = lane >> 4, l16 = lane & 15;
  const int wid = tid >> 6;
  const int wm = (wid & 1) * 64, wn = (wid >> 1) * 64;

  f32x4 acc[4][4];
#pragma unroll
  for (int i = 0; i < 4; ++i)
#pragma unroll
    for (int j = 0; j < 4; ++j) acc[i][j] = {0.f, 0.f, 0.f, 0.f};

  for (int k0 = 0; k0 < 2 * DIN; k0 += 32) {
    const bool ph2 = (k0 >= DIN);
    const int kk = k0 & (DIN - 1);
    const u16* Ag = ph2 ? A2g : A1g;
    const u16* Wg = ph2 ? W2g : W1g;
    uint4 av0 = *(const uint4*)(Ag + kk);
    uint4 av1 = *(const uint4*)(Ag + kk + 8);
    uint4 wv0 = *(const uint4*)(Wg + kk);
    uint4 wv1 = *(const uint4*)(Wg + kk + 8);
    __syncthreads();
    *(uint4*)&Asm[srow][scol] = av0;
    *(uint4*)&Asm[srow][scol + 8] = av1;
    *(uint4*)&Wsm[srow][scol] = wv0;
    *(uint4*)&Wsm[srow][scol + 8] = wv1;
    __syncthreads();
    bfrag a[4], b[4];
#pragma unroll
    for (int mi = 0; mi < 4; ++mi)
      a[mi] = *(const bfrag*)&Asm[wm + mi * 16 + l16][quad * 8];
#pragma unroll
    for (int ni = 0; ni < 4; ++ni)
      b[ni] = *(const bfrag*)&Wsm[wn + ni * 16 + l16][quad * 8];
#pragma unroll
    for (int mi = 0; mi < 4; ++mi)
#pragma unroll
      for (int ni = 0; ni < 4; ++ni)
        acc[mi][ni] = __builtin_amdgcn_mfma_f32_16x16x32_bf16(
            a[mi], b[ni], acc[mi][ni], 0, 0, 0);
  }

#pragma unroll
  for (int mi = 0; mi < 4; ++mi)
#pragma unroll
    for (int ni = 0; ni < 4; ++ni)
#pragma unroll
      for (int r = 0; r < 4; ++r) {
        int row = m0 + wm + mi * 16 + quad * 4 + r;
        int col = n0 + wn + ni * 16 + l16;
        long oi = (long)row * DM + col;
        newx[oi] = acc[mi][ni][r] + xres[oi];
      }
}

// ---------------------------------------------------------------------------
// Vector-ALU GEMM with ROW-MAJOR B: C(M,N) = A(M,K) @ B(K,N).
//   EPI_NONE:          fp32 out (xdblT: A=xp_w 64x1024, B=xcT -> 64x8192)
//   EPI_SOFTPLUS_ROW:  softplus(acc + bias[row]) bf16 out
//                      (dtT: A=dtp_w 1024x32, B=xdblT rows 0..31 -> 1024x8192)
// ---------------------------------------------------------------------------
constexpr int EPI_NONE = 0;
constexpr int EPI_SOFTPLUS_ROW = 1;

#define BM 64
#define BN 64
#define BKK 16

template <int EPI, typename TB, typename TO>
__global__ __launch_bounds__(256) void gemmBT_k(
    const float* __restrict__ A,
    const TB* __restrict__ B,
    TO* __restrict__ C, int N,
    const float* __restrict__ bias, int K) {
  __shared__ float As[BKK][BM + 4];
  __shared__ float Bs[BKK][BN + 4];
  const int tid = threadIdx.x;
  const int m0 = blockIdx.y * BM;
  const int n0 = blockIdx.x * BN;
  const int tx = tid & 15;
  const int ty = tid >> 4;
  const int lrow = tid >> 2;        // A-stage: m index 0..63
  const int lcol = (tid & 3) * 4;   // A-stage: k offset 0,4,8,12
  const int kr = tid >> 4;          // B-stage: k index 0..15
  const int nc = (tid & 15) * 4;    // B-stage: n offset

  const float* Arow = A + (long)(m0 + lrow) * K;

  float acc[4][4] = {};
  for (int k0 = 0; k0 < K; k0 += BKK) {
    float4 av = *(const float4*)(Arow + k0 + lcol);
    float4 bv = ld4f_bt(B + (long)(k0 + kr) * N + n0 + nc);
    As[lcol + 0][lrow] = av.x; As[lcol + 1][lrow] = av.y;
    As[lcol + 2][lrow] = av.z; As[lcol + 3][lrow] = av.w;
    Bs[kr][nc + 0] = bv.x; Bs[kr][nc + 1] = bv.y;
    Bs[kr][nc + 2] = bv.z; Bs[kr][nc + 3] = bv.w;
    __syncthreads();
#pragma unroll
    for (int k = 0; k < BKK; ++k) {
      float a[4], b[4];
#pragma unroll
      for (int i = 0; i < 4; ++i) a[i] = As[k][ty * 4 + i];
#pragma unroll
      for (int j = 0; j < 4; ++j) b[j] = Bs[k][tx * 4 + j];
#pragma unroll
      for (int i = 0; i < 4; ++i)
#pragma unroll
        for (int j = 0; j < 4; ++j) acc[i][j] += a[i] * b[j];
    }
    __syncthreads();
  }

#pragma unroll
  for (int i = 0; i < 4; ++i) {
    int r = m0 + ty * 4 + i;
#pragma unroll
    for (int j = 0; j < 4; ++j) {
      int c = n0 + tx * 4 + j;
      float v = acc[i][j];
      if (EPI == EPI_SOFTPLUS_ROW) {
        v += bias[r];
        v = (v > 20.f) ? v : log1pf(__expf(v));
      }
      stf(C, (long)r * N + c, v);
    }
  }
}

// ---------------------------------------------------------------------------
// Fused depthwise causal conv (k=4) + bias + silu + TRANSPOSE.
// in  xs: (MROWS x DIN) bf16  ->  out xcT: (DIN x MROWS) bf16.
// 64x64 tiles; 3-column halo for the causal window; halo zeroed at batch head.
// ---------------------------------------------------------------------------
__global__ __launch_bounds__(256) void convT_k(
    const bf16* __restrict__ xs, const float* __restrict__ w,
    const float* __restrict__ b, bf16* __restrict__ xcT) {
  __shared__ u16 T[64][72];   // [d_local][bt_local + 3 halo]
  int c0 = blockIdx.x * 64;   // d
  int r0 = blockIdx.y * 64;   // bt
  int tid = threadIdx.x;
  int tr = tid >> 2;          // 0..63
  int tc = (tid & 3) * 16;    // 0,16,32,48

  // main tile: row r0+tr, cols c0+tc..+15 -> T[tc+j][tr+3]
  const u16* src = (const u16*)xs + (long)(r0 + tr) * DIN + c0 + tc;
  uint4 v0 = *(const uint4*)src;
  uint4 v1 = *(const uint4*)(src + 8);
  u16 tmp[16];
  *(uint4*)tmp = v0;
  *(uint4*)(tmp + 8) = v1;
#pragma unroll
  for (int j = 0; j < 16; ++j) T[tc + j][tr + 3] = tmp[j];
  // halo: rows r0-3..r0-1 (zero at batch head), threads 0..11
  bool head = (r0 & (L_SZ - 1)) == 0;
  if (tid < 12) {
    int hr = tid >> 2;            // 0..2
    int seg = (tid & 3) * 16;
    if (head) {
#pragma unroll
      for (int j = 0; j < 16; ++j) T[seg + j][hr] = 0;
    } else {
      const u16* hs = (const u16*)xs + (long)(r0 - 3 + hr) * DIN + c0 + seg;
      uint4 h0 = *(const uint4*)hs;
      uint4 h1 = *(const uint4*)(hs + 8);
      u16 ht[16];
      *(uint4*)ht = h0;
      *(uint4*)(ht + 8) = h1;
#pragma unroll
      for (int j = 0; j < 16; ++j) T[seg + j][hr] = ht[j];
    }
  }
  __syncthreads();

  // compute: thread -> d_local = tr, bt_local base = tc
  int d = c0 + tr;
  float w0 = w[d * 4 + 0], w1 = w[d * 4 + 1], w2 = w[d * 4 + 2], w3 = w[d * 4 + 3];
  float bd = b[d];
  float X[19];
#pragma unroll
  for (int k = 0; k < 19; ++k) X[k] = b2f(T[tr][tc + k]);
  u16 o[16];
#pragma unroll
  for (int j = 0; j < 16; ++j) {
    float acc = bd + w0 * X[j] + w1 * X[j + 1] + w2 * X[j + 2] + w3 * X[j + 3];
    o[j] = f2b(acc / (1.f + __expf(-acc)));
  }
  u16* dst = (u16*)xcT + (long)d * MROWS + r0 + tc;
  *(uint4*)dst = *(uint4*)o;
  *(uint4*)(dst + 8) = *(uint4*)(o + 8);
}

// ---------------------------------------------------------------------------
// Merged bidirectional selective scan + skip (u*D). 1024 blocks:
// blocks [0,512) = dir1, [512,1024) = dir2.
// dtT,uT: (DIN x MROWS) bf16 t-contiguous; B/C from xdblT rows 32..63 fp32.
// Output y UNGATED, normal (bt,d) layout bf16 (gating in mgemm epilogue).
//
// R2 restructure: unroll-2 with two NAMED buffer sets (no rotation movs),
// prefetch for group g+2 issued right after group g's last use, pinned with
// sched_barrier(0) so the machine scheduler cannot sink the loads back to
// their uses (R1 lesson: launch_bounds alone did not stop the sinking;
// VGPR stayed 44 = pipeline collapsed). Store base is wave-uniform per step
// (saddr form), VGPR offset is just d.
// ---------------------------------------------------------------------------
__global__ __launch_bounds__(256, 4) void scan_k(
    const u16* __restrict__ dtT1, const u16* __restrict__ dtT2,
    const u16* __restrict__ uT1, const u16* __restrict__ uT2,
    const float* __restrict__ xd1, const float* __restrict__ xd2,
    const float* __restrict__ Alog1, const float* __restrict__ Alog2,
    const float* __restrict__ D1, const float* __restrict__ D2,
    bf16* __restrict__ y1, bf16* __restrict__ y2) {
  int blk = blockIdx.x;
  int dir = blk >> 9;
  int idx = blk & 511;
  int tid = threadIdx.x;
  int s = tid & 15;
  int gi = tid >> 4;
  int b = idx >> 6;
  int d = ((idx & 63) << 4) + gi;
  const u16* dtT = dir ? dtT2 : dtT1;
  const u16* uT = dir ? uT2 : uT1;
  const float* xd = dir ? xd2 : xd1;
  const float* Alog = dir ? Alog2 : Alog1;
  const float* Dp = dir ? D2 : D1;
  bf16* out = dir ? y2 : y1;

  // A2 = A * log2(e); da = 2^(dt * A2)
  float A2 = -__expf(Alog[d * DSTATE + s]) * 1.4426950408889634f;
  float Dd = Dp[d];
  float h = 0.f;
  const u16* pdt = dtT + (long)d * MROWS + b * L_SZ;
  const u16* pu = uT + (long)d * MROWS + b * L_SZ;
  const float* pB = xd + (long)(DTRANK + s) * MROWS + b * L_SZ;
  const float* pC = xd + (long)(DTRANK + DSTATE + s) * MROWS + b * L_SZ;
  bf16* outb = out + (long)b * L_SZ * DIN;   // + t*DIN + d
  const int iod = d;

  union F8 { float4 v[2]; float a[8]; };
  union U8 { uint4 v; u16 a[8]; };
  constexpr int NG = L_SZ / 8;   // 128 groups of 8 timesteps

  U8 dtA, uA, dtB, uB;
  F8 BA, CA, BB, CB;

#define LOADSET(DT, UU, BS, CS, k)                                         \
  {                                                                        \
    int off_ = (k) * 8;                                                    \
    DT.v = *(const uint4*)(pdt + off_);                                    \
    UU.v = *(const uint4*)(pu + off_);                                     \
    BS.v[0] = *(const float4*)(pB + off_);                                 \
    BS.v[1] = *(const float4*)(pB + off_ + 4);                             \
    CS.v[0] = *(const float4*)(pC + off_);                                 \
    CS.v[1] = *(const float4*)(pC + off_ + 4);                             \
  }

#define COMPUTE8(DT, UU, BS, CS, gidx)                                     \
  {                                                                        \
    const bf16* og_ = outb + (long)(gidx) * 8 * DIN;                       \
    _Pragma("unroll")                                                      \
    for (int j = 0; j < 8; ++j) {                                          \
      float dtv = b2f(DT.a[j]);                                            \
      float uv = b2f(UU.a[j]);                                             \
      float da = fexp2(dtv * A2);                                          \
      h = da * h + (dtv * uv) * BS.a[j];                                   \
      float p = row16_sum(h * CS.a[j]);                                    \
      if (s == 0) stf((bf16*)(og_ + (long)j * DIN), iod, p + Dd * uv);     \
    }                                                                      \
  }

  LOADSET(dtA, uA, BA, CA, 0);
  LOADSET(dtB, uB, BB, CB, 1);
  __builtin_amdgcn_sched_barrier(0);

  for (int g = 0; g < NG; g += 2) {
    COMPUTE8(dtA, uA, BA, CA, g);
    if (g + 2 < NG) LOADSET(dtA, uA, BA, CA, g + 2);
    __builtin_amdgcn_sched_barrier(0);
    COMPUTE8(dtB, uB, BB, CB, g + 1);
    if (g + 3 < NG) LOADSET(dtB, uB, BB, CB, g + 3);
    __builtin_amdgcn_sched_barrier(0);
  }
#undef LOADSET
#undef COMPUTE8
}

// ---------------------------------------------------------------------------
// LayerNorm over last dim (512). fp32 in; fp32 out + optional bf16 copy.
// Safe in-place (all reads precede all writes per thread; one block per row).
// ---------------------------------------------------------------------------
__global__ __launch_bounds__(256) void ln_k(
    const float* __restrict__ xin, const float* __restrict__ g,
    const float* __restrict__ bb, float* __restrict__ out,
    bf16* __restrict__ outb) {
  int row = blockIdx.x;
  const float* p = xin + (long)row * DM;
  int tid = threadIdx.x;
  float x0 = p[tid], x1 = p[tid + 256];
  float sum = x0 + x1;
  float sq = x0 * x0 + x1 * x1;
#pragma unroll
  for (int o = 1; o < 64; o <<= 1) {
    sum += __shfl_xor(sum, o, 64);
    sq += __shfl_xor(sq, o, 64);
  }
  __shared__ float ssum[4], ssq[4];
  int wv = tid >> 6;
  if ((tid & 63) == 0) { ssum[wv] = sum; ssq[wv] = sq; }
  __syncthreads();
  sum = ssum[0] + ssum[1] + ssum[2] + ssum[3];
  sq = ssq[0] + ssq[1] + ssq[2] + ssq[3];
  float mean = sum * (1.f / DM);
  float var = sq * (1.f / DM) - mean * mean;
  float rstd = rsqrtf(var + 1e-5f);
  float v0 = (x0 - mean) * rstd * g[tid] + bb[tid];
  float v1 = (x1 - mean) * rstd * g[tid + 256] + bb[tid + 256];
  out[(long)row * DM + tid] = v0;
  out[(long)row * DM + tid + 256] = v1;
  if (outb) {
    stf(outb, (long)row * DM + tid, v0);
    stf(outb, (long)row * DM + tid + 256, v1);
  }
}

// ---------------------------------------------------------------------------
// Orchestration. Workspace: 6 slots x 16 MB = 96 MB (proven safe at R4):
//  A[0,16):  xs1 -> y1 -> gated y1 -> outacc(fp32)
//  B[16,32): xcT1 (=uT1, live thru scan) -> xln fp32
//  C[32,48): dtT1 (live thru scan) -> newx fp32 -> ffn head (32 MB span C+D)
//  D[48,64): xs2 -> y2 -> gated y2 -> ffn tail
//  E[64,80): xcT2 (=uT2) -> xln bf16
//  F[80,96): dtT2
// d_out (16 MB): bf16 weights [0,10 MB) + xdblT1 @10MB + xdblT2 @12MB (fp32);
//               all dead before FFN-down; LN2 overwrites d_out at the end.
// x and in-proj/gate A-operands convert fp32->bf16 inline in mgemm staging.
// ---------------------------------------------------------------------------
extern "C" void kernel_launch(void* const* d_in, const int* in_sizes, int n_in,
                              void* d_out, int out_size, void* d_ws, size_t ws_size,
                              hipStream_t stream) {
  const float* x = (const float*)d_in[0];
  const float* in1_w = (const float*)d_in[1];
  const float* conv1_w = (const float*)d_in[2];
  const float* conv1_b = (const float*)d_in[3];
  const float* xp1_w = (const float*)d_in[4];
  const float* dtp1_w = (const float*)d_in[5];
  const float* dtp1_b = (const float*)d_in[6];
  const float* Alog1 = (const float*)d_in[7];
  const float* D1 = (const float*)d_in[8];
  const float* outp1_w = (const float*)d_in[9];
  const float* in2_w = (const float*)d_in[10];
  const float* conv2_w = (const float*)d_in[11];
  const float* conv2_b = (const float*)d_in[12];
  const float* xp2_w = (const float*)d_in[13];
  const float* dtp2_w = (const float*)d_in[14];
  const float* dtp2_b = (const float*)d_in[15];
  const float* Alog2 = (const float*)d_in[16];
  const float* D2 = (const float*)d_in[17];
  const float* outp2_w = (const float*)d_in[18];
  const float* c1_w = (const float*)d_in[19];
  const float* c1_b = (const float*)d_in[20];
  const float* c2_w = (const float*)d_in[21];
  const float* c2_b = (const float*)d_in[22];
  const float* ln1_g = (const float*)d_in[23];
  const float* ln1_b = (const float*)d_in[24];
  const float* ln2_g = (const float*)d_in[25];
  const float* ln2_b = (const float*)d_in[26];

  const long MB = 1024L * 1024;
  char* wsb = (char*)d_ws;
  bf16* A = (bf16*)(wsb + 0 * MB);
  bf16* B = (bf16*)(wsb + 16 * MB);
  bf16* C = (bf16*)(wsb + 32 * MB);
  bf16* D = (bf16*)(wsb + 48 * MB);
  bf16* E = (bf16*)(wsb + 64 * MB);
  bf16* F = (bf16*)(wsb + 80 * MB);
  float* Bf = (float*)B;   // xln fp32
  float* Cf = (float*)C;   // newx fp32
  float* Af = (float*)A;   // outacc fp32
  bf16* ffn = C;           // 32 MB span C+D, ldc = 2048

  char* ob = (char*)d_out;
  bf16* in1b = (bf16*)(ob + 0 * MB);   // 1M elems (2 MB)
  bf16* in2b = (bf16*)(ob + 2 * MB);
  bf16* o1b = (bf16*)(ob + 4 * MB);    // 512K (1 MB)
  bf16* o2b = (bf16*)(ob + 5 * MB);
  bf16* c1b = (bf16*)(ob + 6 * MB);    // 1M (2 MB)
  bf16* c2b = (bf16*)(ob + 8 * MB);
  float* xdT1 = (float*)(ob + 10 * MB);  // 64x8192 fp32 (2 MB)
  float* xdT2 = (float*)(ob + 12 * MB);

  dim3 blk(256);
  dim3 gP(DIN / 128, MROWS / 128);      // N=1024 MFMA
  dim3 gM(DM / 128, MROWS / 128);       // N=512 MFMA
  dim3 gF(DFF / 128, MROWS / 128);      // N=2048 MFMA
  dim3 gC(DIN / 64, MROWS / 64);        // convT tiles
  dim3 gX(MROWS / BN, 64 / BM);         // xdblT: M=64
  dim3 gD(MROWS / BN, DIN / BM);        // dtT: M=1024

  // ---- weight conversions into d_out ----
  cvt_k<<<(2 * DIN * DM) / 256, blk, 0, stream>>>(in1_w, in1b, 2 * DIN * DM);
  cvt_k<<<(2 * DIN * DM) / 256, blk, 0, stream>>>(in2_w, in2b, 2 * DIN * DM);
  cvt_k<<<(DM * DIN) / 256, blk, 0, stream>>>(outp1_w, o1b, DM * DIN);
  cvt_k<<<(DM * DIN) / 256, blk, 0, stream>>>(outp2_w, o2b, DM * DIN);
  cvt_k<<<(DFF * DM) / 256, blk, 0, stream>>>(c1_w, c1b, DFF * DM);
  cvt_k<<<(DM * DFF) / 256, blk, 0, stream>>>(c2_w, c2b, DM * DFF);

  // ---- direction 1 prelude ----
  mgemm_k<MEPI_STORE_BF16, false, float, bf16><<<gP, blk, 0, stream>>>(
      x, DM, in1b, DM, A, DIN, nullptr, nullptr, DM);                    // xs1
  convT_k<<<gC, blk, 0, stream>>>(A, conv1_w, conv1_b, B);               // xcT1
  gemmBT_k<EPI_NONE, bf16, float><<<gX, blk, 0, stream>>>(
      xp1_w, B, xdT1, MROWS, nullptr, DIN);                              // xdblT1
  gemmBT_k<EPI_SOFTPLUS_ROW, float, bf16><<<gD, blk, 0, stream>>>(
      dtp1_w, xdT1, C, MROWS, dtp1_b, DTRANK);                           // dtT1

  // ---- direction 2 prelude ----
  mgemm_k<MEPI_STORE_BF16, true, float, bf16><<<gP, blk, 0, stream>>>(
      x, DM, in2b, DM, D, DIN, nullptr, nullptr, DM);                    // xs2
  convT_k<<<gC, blk, 0, stream>>>(D, conv2_w, conv2_b, E);               // xcT2
  gemmBT_k<EPI_NONE, bf16, float><<<gX, blk, 0, stream>>>(
      xp2_w, E, xdT2, MROWS, nullptr, DIN);                              // xdblT2
  gemmBT_k<EPI_SOFTPLUS_ROW, float, bf16><<<gD, blk, 0, stream>>>(
      dtp2_w, xdT2, F, MROWS, dtp2_b, DTRANK);                           // dtT2

  // ---- merged bidirectional scan: y1 -> A, y2 -> D ----
  scan_k<<<2 * B_SZ * (DIN / 16), blk, 0, stream>>>(
      (const u16*)C, (const u16*)F, (const u16*)B, (const u16*)E,
      xdT1, xdT2, Alog1, Alog2, D1, D2, A, D);

  // ---- gates (in-place over y) ----
  mgemm_k<MEPI_GATE, false, float, bf16><<<gP, blk, 0, stream>>>(
      x, DM, in1b + (long)DIN * DM, DM, A, DIN, nullptr, nullptr, DM);
  mgemm_k<MEPI_GATE, true, float, bf16><<<gP, blk, 0, stream>>>(
      x, DM, in2b + (long)DIN * DM, DM, D, DIN, nullptr, nullptr, DM);

  // ---- merge: newx = y1@W1^T + flip(y2)@W2^T + x -> C (fp32) ----
  mmerge_k<<<gM, blk, 0, stream>>>(A, D, o1b, o2b, x, Cf);

  // ---- LN1: fp32 -> B, bf16 -> E ----
  ln_k<<<MROWS, blk, 0, stream>>>(Cf, ln1_g, ln1_b, Bf, E);

  // ---- FFN (single up, single down) ----
  mgemm_k<MEPI_BIAS_GELU, false, bf16, bf16><<<gF, blk, 0, stream>>>(
      E, DM, c1b, DM, ffn, DFF, c1_b, nullptr, DM);
  mgemm_k<MEPI_BIAS_RES, false, bf16, float><<<gM, blk, 0, stream>>>(
      ffn, DFF, c2b, DFF, Af, DM, c2_b, Bf, DFF);

  // ---- LN2 -> d_out (weights/xdblT scratch dead) ----
  ln_k<<<MROWS, blk, 0, stream>>>(Af, ln2_g, ln2_b, (float*)d_out, nullptr);
}

// Round 4
// 933.162 us; speedup vs baseline: 1.0689x; 1.0689x over previous
//
#include <hip/hip_runtime.h>
#include <hip/hip_bf16.h>
#include <math.h>

// ---------------------------------------------------------------------------
// Problem constants
// ---------------------------------------------------------------------------
#define B_SZ 8
#define L_SZ 1024
#define DM 512          // d_model
#define DFF 2048        // d_ff
#define DIN 1024        // expand * d_model
#define DSTATE 16
#define DTRANK 32
#define MROWS (B_SZ * L_SZ)   // 8192

typedef __hip_bfloat16 bf16;
typedef unsigned short u16;
using f32x4 = __attribute__((ext_vector_type(4))) float;
using u32x4 = __attribute__((ext_vector_type(4))) unsigned int;
using bfrag = __attribute__((ext_vector_type(8))) short;   // 8 bf16 = 4 VGPR

__device__ inline float ldf(const float* p, long i) { return p[i]; }
__device__ inline float ldf(const bf16* p, long i) {
  return __uint_as_float((unsigned)((const u16*)p)[i] << 16);
}
__device__ inline void stf(float* p, long i, float v) { p[i] = v; }
__device__ inline void stf(bf16* p, long i, float v) { p[i] = __float2bfloat16(v); }
__device__ inline float b2f(u16 x) {
  return __uint_as_float((unsigned)x << 16);
}
__device__ inline u16 f2b(float v) {
  union { bf16 h; u16 u; } c;
  c.h = __float2bfloat16(v);
  return c.u;
}

// Raw v_exp_f32: computes 2^x in one trans-pipe instruction.
__device__ inline float fexp2(float x) {
  float r;
  asm("v_exp_f32 %0, %1" : "=v"(r) : "v"(x));
  return r;
}

// B-element loader (4 consecutive): fp32 direct, bf16 convert.
__device__ inline float4 ld4f_bt(const float* p) { return *(const float4*)p; }
__device__ inline float4 ld4f_bt(const bf16* p) {
  ushort4 u = *(const ushort4*)p;
  float4 v;
  v.x = b2f(u.x); v.y = b2f(u.y); v.z = b2f(u.z); v.w = b2f(u.w);
  return v;
}

// 16-element row loader into packed bf16 (2 x uint4). bf16 src: direct.
// fp32 src: inline RNE convert (matches cvt path numerically).
__device__ inline void ld16(const bf16* p, uint4& lo, uint4& hi) {
  lo = *(const uint4*)p;
  hi = *(const uint4*)((const u16*)p + 8);
}
__device__ inline void ld16(const float* p, uint4& lo, uint4& hi) {
  float4 a = *(const float4*)p, b = *(const float4*)(p + 4);
  float4 c = *(const float4*)(p + 8), d = *(const float4*)(p + 12);
  union { uint4 v; u16 s[8]; } L, H;
  L.s[0] = f2b(a.x); L.s[1] = f2b(a.y); L.s[2] = f2b(a.z); L.s[3] = f2b(a.w);
  L.s[4] = f2b(b.x); L.s[5] = f2b(b.y); L.s[6] = f2b(b.z); L.s[7] = f2b(b.w);
  H.s[0] = f2b(c.x); H.s[1] = f2b(c.y); H.s[2] = f2b(c.z); H.s[3] = f2b(c.w);
  H.s[4] = f2b(d.x); H.s[5] = f2b(d.y); H.s[6] = f2b(d.z); H.s[7] = f2b(d.w);
  lo = L.v; hi = H.v;
}

// Fused DPP rotate-add reduce within 16-lane row: v_add_f32 dst, dpp(src0), src1.
// 4 instructions total (vs 8 for mov_dpp+add). All lanes end with the full sum.
__device__ inline float dpp_add_r8(float x) {
  float r; asm("v_add_f32 %0, %1, %2 row_ror:8" : "=v"(r) : "v"(x), "v"(x)); return r;
}
__device__ inline float dpp_add_r4(float x) {
  float r; asm("v_add_f32 %0, %1, %2 row_ror:4" : "=v"(r) : "v"(x), "v"(x)); return r;
}
__device__ inline float dpp_add_r2(float x) {
  float r; asm("v_add_f32 %0, %1, %2 row_ror:2" : "=v"(r) : "v"(x), "v"(x)); return r;
}
__device__ inline float dpp_add_r1(float x) {
  float r; asm("v_add_f32 %0, %1, %2 row_ror:1" : "=v"(r) : "v"(x), "v"(x)); return r;
}
__device__ inline float row16_sum(float x) {
  return dpp_add_r1(dpp_add_r2(dpp_add_r4(dpp_add_r8(x))));
}

// Volatile asm global loads: CANNOT be sunk/moved by any compiler pass.
// (R1/R3 lesson: launch_bounds and sched_barrier both failed to keep the
// software pipeline alive; VGPR 44->36 proved loads were sunk to uses.)
__device__ inline void gl4(u32x4& d, const void* a) {
  asm volatile("global_load_dwordx4 %0, %1, off" : "=v"(d) : "v"(a));
}
__device__ inline void gl4o16(u32x4& d, const void* a) {   // +16 bytes
  asm volatile("global_load_dwordx4 %0, %1, off offset:16" : "=v"(d) : "v"(a));
}
// Counted vmcnt wait. "memory" clobber: compiler stores may not cross it
// (keeps the vmcnt queue composition deterministic). sched_barrier after
// per guide rule #18 (register-only ops can otherwise hoist past the wait).
template <int N>
__device__ inline void wait_vm() {
  asm volatile("s_waitcnt vmcnt(%0)" :: "n"(N) : "memory");
  __builtin_amdgcn_sched_barrier(0);
}

// ---------------------------------------------------------------------------
// fp32 -> bf16 convert (weights -> d_out scratch)
// ---------------------------------------------------------------------------
__global__ __launch_bounds__(256) void cvt_k(const float* __restrict__ s,
                                             bf16* __restrict__ d, int n) {
  int i = blockIdx.x * 256 + threadIdx.x;
  if (i < n) d[i] = __float2bfloat16(s[i]);
}

// ---------------------------------------------------------------------------
// bf16 MFMA GEMM: C(M,N) = A(M,K) @ W(N,K)^T, fp32 accumulate.
// 128x128 tile, BK=32, 4 waves, each 64x64 via 4x4 v_mfma_f32_16x16x32_bf16.
// TA may be float (inline bf16 conversion in staging). W always bf16.
// ---------------------------------------------------------------------------
constexpr int MEPI_STORE_BF16 = 0;
constexpr int MEPI_GATE = 1;        // C[oi] = C[oi] * silu(acc), bf16 in-place
constexpr int MEPI_BIAS_GELU = 2;   // bf16 out
constexpr int MEPI_BIAS_RES = 3;    // fp32 out = acc + bias + res

template <int EPI, bool FLIPA, typename TA, typename TO>
__global__ __launch_bounds__(256) void mgemm_k(
    const TA* __restrict__ Ab, int lda,
    const bf16* __restrict__ Wb, int ldw,
    TO* __restrict__ C, int ldc,
    const float* __restrict__ bias,
    const float* __restrict__ res,
    int K) {
  __shared__ u16 Asm[128][40];
  __shared__ u16 Wsm[128][40];
  const int tid = threadIdx.x;
  const int m0 = blockIdx.y * 128;
  const int n0 = blockIdx.x * 128;

  const int srow = tid >> 1;
  const int scol = (tid & 1) * 16;
  int ar = m0 + srow;
  if (FLIPA) { int t = ar & (L_SZ - 1); ar = (ar - t) + (L_SZ - 1 - t); }
  const TA* Ag = Ab + (long)ar * lda + scol;
  const u16* Wg = (const u16*)Wb + (long)(n0 + srow) * ldw + scol;

  const int lane = tid & 63, quad = lane >> 4, l16 = lane & 15;
  const int wid = tid >> 6;
  const int wm = (wid & 1) * 64, wn = (wid >> 1) * 64;

  f32x4 acc[4][4];
#pragma unroll
  for (int i = 0; i < 4; ++i)
#pragma unroll
    for (int j = 0; j < 4; ++j) acc[i][j] = {0.f, 0.f, 0.f, 0.f};

  for (int k0 = 0; k0 < K; k0 += 32) {
    uint4 av0, av1, wv0, wv1;
    ld16(Ag + k0, av0, av1);
    ld16((const bf16*)(Wg + k0), wv0, wv1);
    __syncthreads();
    *(uint4*)&Asm[srow][scol] = av0;
    *(uint4*)&Asm[srow][scol + 8] = av1;
    *(uint4*)&Wsm[srow][scol] = wv0;
    *(uint4*)&Wsm[srow][scol + 8] = wv1;
    __syncthreads();
    bfrag a[4], b[4];
#pragma unroll
    for (int mi = 0; mi < 4; ++mi)
      a[mi] = *(const bfrag*)&Asm[wm + mi * 16 + l16][quad * 8];
#pragma unroll
    for (int ni = 0; ni < 4; ++ni)
      b[ni] = *(const bfrag*)&Wsm[wn + ni * 16 + l16][quad * 8];
#pragma unroll
    for (int mi = 0; mi < 4; ++mi)
#pragma unroll
      for (int ni = 0; ni < 4; ++ni)
        acc[mi][ni] = __builtin_amdgcn_mfma_f32_16x16x32_bf16(
            a[mi], b[ni], acc[mi][ni], 0, 0, 0);
  }

#pragma unroll
  for (int mi = 0; mi < 4; ++mi)
#pragma unroll
    for (int ni = 0; ni < 4; ++ni)
#pragma unroll
      for (int r = 0; r < 4; ++r) {
        int row = m0 + wm + mi * 16 + quad * 4 + r;
        int col = n0 + wn + ni * 16 + l16;
        long oi = (long)row * ldc + col;
        float v = acc[mi][ni][r];
        if (EPI == MEPI_STORE_BF16) {
          stf(C, oi, v);
        } else if (EPI == MEPI_GATE) {
          float y = ldf((const bf16*)C, oi);
          float sz = v / (1.f + __expf(-v));
          stf(C, oi, y * sz);
        } else if (EPI == MEPI_BIAS_GELU) {
          v += bias[col];
          v = 0.5f * v * (1.f + erff(v * 0.70710678118654752440f));
          stf(C, oi, v);
        } else if (EPI == MEPI_BIAS_RES) {
          ((float*)C)[oi] = v + bias[col] + res[oi];
        }
      }
}

// ---------------------------------------------------------------------------
// MFMA merge: newx(M,DM) = y1 @ W1^T + flip_L(y2) @ W2^T + xres (fp32 out).
// ---------------------------------------------------------------------------
__global__ __launch_bounds__(256) void mmerge_k(
    const bf16* __restrict__ y1, const bf16* __restrict__ y2,
    const bf16* __restrict__ W1, const bf16* __restrict__ W2,
    const float* __restrict__ xres, float* __restrict__ newx) {
  __shared__ u16 Asm[128][40];
  __shared__ u16 Wsm[128][40];
  const int tid = threadIdx.x;
  const int m0 = blockIdx.y * 128;
  const int n0 = blockIdx.x * 128;

  const int srow = tid >> 1;
  const int scol = (tid & 1) * 16;
  int r1 = m0 + srow;
  int tt = r1 & (L_SZ - 1);
  int r2 = (r1 - tt) + (L_SZ - 1 - tt);
  const u16* A1g = (const u16*)y1 + (long)r1 * DIN + scol;
  const u16* A2g = (const u16*)y2 + (long)r2 * DIN + scol;
  const u16* W1g = (const u16*)W1 + (long)(n0 + srow) * DIN + scol;
  const u16* W2g = (const u16*)W2 + (long)(n0 + srow) * DIN + scol;

  const int lane = tid & 63, quad = lane >> 4, l16 = lane & 15;
  const int wid = tid >> 6;
  const int wm = (wid & 1) * 64, wn = (wid >> 1) * 64;

  f32x4 acc[4][4];
#pragma unroll
  for (int i = 0; i < 4; ++i)
#pragma unroll
    for (int j = 0; j < 4; ++j) acc[i][j] = {0.f, 0.f, 0.f, 0.f};

  for (int k0 = 0; k0 < 2 * DIN; k0 += 32) {
    const bool ph2 = (k0 >= DIN);
    const int kk = k0 & (DIN - 1);
    const u16* Ag = ph2 ? A2g : A1g;
    const u16* Wg = ph2 ? W2g : W1g;
    uint4 av0 = *(const uint4*)(Ag + kk);
    uint4 av1 = *(const uint4*)(Ag + kk + 8);
    uint4 wv0 = *(const uint4*)(Wg + kk);
    uint4 wv1 = *(const uint4*)(Wg + kk + 8);
    __syncthreads();
    *(uint4*)&Asm[srow][scol] = av0;
    *(uint4*)&Asm[srow][scol + 8] = av1;
    *(uint4*)&Wsm[srow][scol] = wv0;
    *(uint4*)&Wsm[srow][scol + 8] = wv1;
    __syncthreads();
    bfrag a[4], b[4];
#pragma unroll
    for (int mi = 0; mi < 4; ++mi)
      a[mi] = *(const bfrag*)&Asm[wm + mi * 16 + l16][quad * 8];
#pragma unroll
    for (int ni = 0; ni < 4; ++ni)
      b[ni] = *(const bfrag*)&Wsm[wn + ni * 16 + l16][quad * 8];
#pragma unroll
    for (int mi = 0; mi < 4; ++mi)
#pragma unroll
      for (int ni = 0; ni < 4; ++ni)
        acc[mi][ni] = __builtin_amdgcn_mfma_f32_16x16x32_bf16(
            a[mi], b[ni], acc[mi][ni], 0, 0, 0);
  }

#pragma unroll
  for (int mi = 0; mi < 4; ++mi)
#pragma unroll
    for (int ni = 0; ni < 4; ++ni)
#pragma unroll
      for (int r = 0; r < 4; ++r) {
        int row = m0 + wm + mi * 16 + quad * 4 + r;
        int col = n0 + wn + ni * 16 + l16;
        long oi = (long)row * DM + col;
        newx[oi] = acc[mi][ni][r] + xres[oi];
      }
}

// ---------------------------------------------------------------------------
// Vector-ALU GEMM with ROW-MAJOR B: C(M,N) = A(M,K) @ B(K,N).
//   EPI_NONE:          fp32 out (xdblT: A=xp_w 64x1024, B=xcT -> 64x8192)
//   EPI_SOFTPLUS_ROW:  softplus(acc + bias[row]) bf16 out
//                      (dtT: A=dtp_w 1024x32, B=xdblT rows 0..31 -> 1024x8192)
// ---------------------------------------------------------------------------
constexpr int EPI_NONE = 0;
constexpr int EPI_SOFTPLUS_ROW = 1;

#define BM 64
#define BN 64
#define BKK 16

template <int EPI, typename TB, typename TO>
__global__ __launch_bounds__(256) void gemmBT_k(
    const float* __restrict__ A,
    const TB* __restrict__ B,
    TO* __restrict__ C, int N,
    const float* __restrict__ bias, int K) {
  __shared__ float As[BKK][BM + 4];
  __shared__ float Bs[BKK][BN + 4];
  const int tid = threadIdx.x;
  const int m0 = blockIdx.y * BM;
  const int n0 = blockIdx.x * BN;
  const int tx = tid & 15;
  const int ty = tid >> 4;
  const int lrow = tid >> 2;        // A-stage: m index 0..63
  const int lcol = (tid & 3) * 4;   // A-stage: k offset 0,4,8,12
  const int kr = tid >> 4;          // B-stage: k index 0..15
  const int nc = (tid & 15) * 4;    // B-stage: n offset

  const float* Arow = A + (long)(m0 + lrow) * K;

  float acc[4][4] = {};
  for (int k0 = 0; k0 < K; k0 += BKK) {
    float4 av = *(const float4*)(Arow + k0 + lcol);
    float4 bv = ld4f_bt(B + (long)(k0 + kr) * N + n0 + nc);
    As[lcol + 0][lrow] = av.x; As[lcol + 1][lrow] = av.y;
    As[lcol + 2][lrow] = av.z; As[lcol + 3][lrow] = av.w;
    Bs[kr][nc + 0] = bv.x; Bs[kr][nc + 1] = bv.y;
    Bs[kr][nc + 2] = bv.z; Bs[kr][nc + 3] = bv.w;
    __syncthreads();
#pragma unroll
    for (int k = 0; k < BKK; ++k) {
      float a[4], b[4];
#pragma unroll
      for (int i = 0; i < 4; ++i) a[i] = As[k][ty * 4 + i];
#pragma unroll
      for (int j = 0; j < 4; ++j) b[j] = Bs[k][tx * 4 + j];
#pragma unroll
      for (int i = 0; i < 4; ++i)
#pragma unroll
        for (int j = 0; j < 4; ++j) acc[i][j] += a[i] * b[j];
    }
    __syncthreads();
  }

#pragma unroll
  for (int i = 0; i < 4; ++i) {
    int r = m0 + ty * 4 + i;
#pragma unroll
    for (int j = 0; j < 4; ++j) {
      int c = n0 + tx * 4 + j;
      float v = acc[i][j];
      if (EPI == EPI_SOFTPLUS_ROW) {
        v += bias[r];
        v = (v > 20.f) ? v : log1pf(__expf(v));
      }
      stf(C, (long)r * N + c, v);
    }
  }
}

// ---------------------------------------------------------------------------
// Fused depthwise causal conv (k=4) + bias + silu + TRANSPOSE.
// in  xs: (MROWS x DIN) bf16  ->  out xcT: (DIN x MROWS) bf16.
// 64x64 tiles; 3-column halo for the causal window; halo zeroed at batch head.
// ---------------------------------------------------------------------------
__global__ __launch_bounds__(256) void convT_k(
    const bf16* __restrict__ xs, const float* __restrict__ w,
    const float* __restrict__ b, bf16* __restrict__ xcT) {
  __shared__ u16 T[64][72];   // [d_local][bt_local + 3 halo]
  int c0 = blockIdx.x * 64;   // d
  int r0 = blockIdx.y * 64;   // bt
  int tid = threadIdx.x;
  int tr = tid >> 2;          // 0..63
  int tc = (tid & 3) * 16;    // 0,16,32,48

  // main tile: row r0+tr, cols c0+tc..+15 -> T[tc+j][tr+3]
  const u16* src = (const u16*)xs + (long)(r0 + tr) * DIN + c0 + tc;
  uint4 v0 = *(const uint4*)src;
  uint4 v1 = *(const uint4*)(src + 8);
  u16 tmp[16];
  *(uint4*)tmp = v0;
  *(uint4*)(tmp + 8) = v1;
#pragma unroll
  for (int j = 0; j < 16; ++j) T[tc + j][tr + 3] = tmp[j];
  // halo: rows r0-3..r0-1 (zero at batch head), threads 0..11
  bool head = (r0 & (L_SZ - 1)) == 0;
  if (tid < 12) {
    int hr = tid >> 2;            // 0..2
    int seg = (tid & 3) * 16;
    if (head) {
#pragma unroll
      for (int j = 0; j < 16; ++j) T[seg + j][hr] = 0;
    } else {
      const u16* hs = (const u16*)xs + (long)(r0 - 3 + hr) * DIN + c0 + seg;
      uint4 h0 = *(const uint4*)hs;
      uint4 h1 = *(const uint4*)(hs + 8);
      u16 ht[16];
      *(uint4*)ht = h0;
      *(uint4*)(ht + 8) = h1;
#pragma unroll
      for (int j = 0; j < 16; ++j) T[seg + j][hr] = ht[j];
    }
  }
  __syncthreads();

  // compute: thread -> d_local = tr, bt_local base = tc
  int d = c0 + tr;
  float w0 = w[d * 4 + 0], w1 = w[d * 4 + 1], w2 = w[d * 4 + 2], w3 = w[d * 4 + 3];
  float bd = b[d];
  float X[19];
#pragma unroll
  for (int k = 0; k < 19; ++k) X[k] = b2f(T[tr][tc + k]);
  u16 o[16];
#pragma unroll
  for (int j = 0; j < 16; ++j) {
    float acc = bd + w0 * X[j] + w1 * X[j + 1] + w2 * X[j + 2] + w3 * X[j + 3];
    o[j] = f2b(acc / (1.f + __expf(-acc)));
  }
  u16* dst = (u16*)xcT + (long)d * MROWS + r0 + tc;
  *(uint4*)dst = *(uint4*)o;
  *(uint4*)(dst + 8) = *(uint4*)(o + 8);
}

// ---------------------------------------------------------------------------
// Merged bidirectional selective scan + skip (u*D). 1024 blocks:
// blocks [0,512) = dir1, [512,1024) = dir2.
// dtT,uT: (DIN x MROWS) bf16 t-contiguous; B/C from xdblT rows 32..63 fp32.
// Output y UNGATED, normal (bt,d) layout bf16 (gating in mgemm epilogue).
//
// R4: hand-pipelined with VOLATILE ASM loads + counted s_waitcnt vmcnt(N).
// Per group of 8 timesteps: 6 global_load_dwordx4 (dt,u,B0,B1,C0,C1) and
// 8 bf16 stores. vmcnt queue invariant at each group's wait point:
//   [L(g) 6][S(g) 8 + L(g+1) 6 newer] -> s_waitcnt vmcnt(14) retires L(g).
// Tail loads are CLAMPED (never skipped) so counts stay uniform.
// Reduce = 4 fused v_add_f32 row_ror DPP instrs; store divergence once/group.
// ---------------------------------------------------------------------------
__global__ __launch_bounds__(256, 4) void scan_k(
    const u16* __restrict__ dtT1, const u16* __restrict__ dtT2,
    const u16* __restrict__ uT1, const u16* __restrict__ uT2,
    const float* __restrict__ xd1, const float* __restrict__ xd2,
    const float* __restrict__ Alog1, const float* __restrict__ Alog2,
    const float* __restrict__ D1, const float* __restrict__ D2,
    bf16* __restrict__ y1, bf16* __restrict__ y2) {
  int blk = blockIdx.x;
  int dir = blk >> 9;
  int idx = blk & 511;
  int tid = threadIdx.x;
  int s = tid & 15;
  int gi = tid >> 4;
  int b = idx >> 6;
  int d = ((idx & 63) << 4) + gi;
  const u16* dtT = dir ? dtT2 : dtT1;
  const u16* uT = dir ? uT2 : uT1;
  const float* xd = dir ? xd2 : xd1;
  const float* Alog = dir ? Alog2 : Alog1;
  const float* Dp = dir ? D2 : D1;
  bf16* out = dir ? y2 : y1;

  // A2 = A * log2(e); da = 2^(dt * A2)
  float A2 = -__expf(Alog[d * DSTATE + s]) * 1.4426950408889634f;
  float Dd = Dp[d];
  float h = 0.f;
  const u16* pdt = dtT + (long)d * MROWS + b * L_SZ;
  const u16* pu = uT + (long)d * MROWS + b * L_SZ;
  const float* pB = xd + (long)(DTRANK + s) * MROWS + b * L_SZ;
  const float* pC = xd + (long)(DTRANK + DSTATE + s) * MROWS + b * L_SZ;
  bf16* outb = out + (long)b * L_SZ * DIN;   // + t*DIN + d

  constexpr int NG = L_SZ / 8;   // 128 groups of 8 timesteps

  struct Grp {
    union { u32x4 v; u16 a[8]; } dt, u;
    union { u32x4 v[2]; float a[8]; } Bv, Cv;
  };
  Grp GA, GB;

#define LOADSET(S, k)                                                       \
  {                                                                         \
    int kc_ = (k) < NG ? (k) : NG - 1;                                      \
    int off_ = kc_ * 8;                                                     \
    gl4(S.dt.v, pdt + off_);                                                \
    gl4(S.u.v, pu + off_);                                                  \
    gl4(S.Bv.v[0], pB + off_);                                              \
    gl4o16(S.Bv.v[1], pB + off_);                                           \
    gl4(S.Cv.v[0], pC + off_);                                              \
    gl4o16(S.Cv.v[1], pC + off_);                                           \
  }

#define COMPUTE8(S, gidx)                                                   \
  {                                                                         \
    float po[8];                                                            \
    _Pragma("unroll")                                                       \
    for (int j = 0; j < 8; ++j) {                                           \
      float dtv = b2f(S.dt.a[j]);                                           \
      float uv = b2f(S.u.a[j]);                                             \
      float da = fexp2(dtv * A2);                                           \
      h = da * h + (dtv * uv) * S.Bv.a[j];                                  \
      float q = row16_sum(h * S.Cv.a[j]);                                   \
      po[j] = q + Dd * uv;                                                  \
    }                                                                       \
    if (s == 0) {                                                           \
      bf16* og_ = outb + (long)(gidx) * 8 * DIN + d;                        \
      _Pragma("unroll")                                                     \
      for (int j = 0; j < 8; ++j) stf(og_, (long)j * DIN, po[j]);           \
    }                                                                       \
  }

  LOADSET(GA, 0);
  LOADSET(GB, 1);
  wait_vm<6>();   // L(0) complete (L(1) may remain in flight)

  for (int g = 0; g < NG; g += 2) {
    // Queue at this point: [L(g) done][S(g-1), L(g+1) maybe in flight]
    COMPUTE8(GA, g);
    LOADSET(GA, g + 2);          // overwrite A-set AFTER its last use
    wait_vm<14>();               // retire through L(g+1): 14 newer ops follow
    COMPUTE8(GB, g + 1);
    LOADSET(GB, g + 3);
    wait_vm<14>();               // retire through L(g+2)
  }
#undef LOADSET
#undef COMPUTE8
}

// ---------------------------------------------------------------------------
// LayerNorm over last dim (512). fp32 in; fp32 out + optional bf16 copy.
// Safe in-place (all reads precede all writes per thread; one block per row).
// ---------------------------------------------------------------------------
__global__ __launch_bounds__(256) void ln_k(
    const float* __restrict__ xin, const float* __restrict__ g,
    const float* __restrict__ bb, float* __restrict__ out,
    bf16* __restrict__ outb) {
  int row = blockIdx.x;
  const float* p = xin + (long)row * DM;
  int tid = threadIdx.x;
  float x0 = p[tid], x1 = p[tid + 256];
  float sum = x0 + x1;
  float sq = x0 * x0 + x1 * x1;
#pragma unroll
  for (int o = 1; o < 64; o <<= 1) {
    sum += __shfl_xor(sum, o, 64);
    sq += __shfl_xor(sq, o, 64);
  }
  __shared__ float ssum[4], ssq[4];
  int wv = tid >> 6;
  if ((tid & 63) == 0) { ssum[wv] = sum; ssq[wv] = sq; }
  __syncthreads();
  sum = ssum[0] + ssum[1] + ssum[2] + ssum[3];
  sq = ssq[0] + ssq[1] + ssq[2] + ssq[3];
  float mean = sum * (1.f / DM);
  float var = sq * (1.f / DM) - mean * mean;
  float rstd = rsqrtf(var + 1e-5f);
  float v0 = (x0 - mean) * rstd * g[tid] + bb[tid];
  float v1 = (x1 - mean) * rstd * g[tid + 256] + bb[tid + 256];
  out[(long)row * DM + tid] = v0;
  out[(long)row * DM + tid + 256] = v1;
  if (outb) {
    stf(outb, (long)row * DM + tid, v0);
    stf(outb, (long)row * DM + tid + 256, v1);
  }
}

// ---------------------------------------------------------------------------
// Orchestration. Workspace: 6 slots x 16 MB = 96 MB (proven safe at R4):
//  A[0,16):  xs1 -> y1 -> gated y1 -> outacc(fp32)
//  B[16,32): xcT1 (=uT1, live thru scan) -> xln fp32
//  C[32,48): dtT1 (live thru scan) -> newx fp32 -> ffn head (32 MB span C+D)
//  D[48,64): xs2 -> y2 -> gated y2 -> ffn tail
//  E[64,80): xcT2 (=uT2) -> xln bf16
//  F[80,96): dtT2
// d_out (16 MB): bf16 weights [0,10 MB) + xdblT1 @10MB + xdblT2 @12MB (fp32);
//               all dead before FFN-down; LN2 overwrites d_out at the end.
// x and in-proj/gate A-operands convert fp32->bf16 inline in mgemm staging.
// ---------------------------------------------------------------------------
extern "C" void kernel_launch(void* const* d_in, const int* in_sizes, int n_in,
                              void* d_out, int out_size, void* d_ws, size_t ws_size,
                              hipStream_t stream) {
  const float* x = (const float*)d_in[0];
  const float* in1_w = (const float*)d_in[1];
  const float* conv1_w = (const float*)d_in[2];
  const float* conv1_b = (const float*)d_in[3];
  const float* xp1_w = (const float*)d_in[4];
  const float* dtp1_w = (const float*)d_in[5];
  const float* dtp1_b = (const float*)d_in[6];
  const float* Alog1 = (const float*)d_in[7];
  const float* D1 = (const float*)d_in[8];
  const float* outp1_w = (const float*)d_in[9];
  const float* in2_w = (const float*)d_in[10];
  const float* conv2_w = (const float*)d_in[11];
  const float* conv2_b = (const float*)d_in[12];
  const float* xp2_w = (const float*)d_in[13];
  const float* dtp2_w = (const float*)d_in[14];
  const float* dtp2_b = (const float*)d_in[15];
  const float* Alog2 = (const float*)d_in[16];
  const float* D2 = (const float*)d_in[17];
  const float* outp2_w = (const float*)d_in[18];
  const float* c1_w = (const float*)d_in[19];
  const float* c1_b = (const float*)d_in[20];
  const float* c2_w = (const float*)d_in[21];
  const float* c2_b = (const float*)d_in[22];
  const float* ln1_g = (const float*)d_in[23];
  const float* ln1_b = (const float*)d_in[24];
  const float* ln2_g = (const float*)d_in[25];
  const float* ln2_b = (const float*)d_in[26];

  const long MB = 1024L * 1024;
  char* wsb = (char*)d_ws;
  bf16* A = (bf16*)(wsb + 0 * MB);
  bf16* B = (bf16*)(wsb + 16 * MB);
  bf16* C = (bf16*)(wsb + 32 * MB);
  bf16* D = (bf16*)(wsb + 48 * MB);
  bf16* E = (bf16*)(wsb + 64 * MB);
  bf16* F = (bf16*)(wsb + 80 * MB);
  float* Bf = (float*)B;   // xln fp32
  float* Cf = (float*)C;   // newx fp32
  float* Af = (float*)A;   // outacc fp32
  bf16* ffn = C;           // 32 MB span C+D, ldc = 2048

  char* ob = (char*)d_out;
  bf16* in1b = (bf16*)(ob + 0 * MB);   // 1M elems (2 MB)
  bf16* in2b = (bf16*)(ob + 2 * MB);
  bf16* o1b = (bf16*)(ob + 4 * MB);    // 512K (1 MB)
  bf16* o2b = (bf16*)(ob + 5 * MB);
  bf16* c1b = (bf16*)(ob + 6 * MB);    // 1M (2 MB)
  bf16* c2b = (bf16*)(ob + 8 * MB);
  float* xdT1 = (float*)(ob + 10 * MB);  // 64x8192 fp32 (2 MB)
  float* xdT2 = (float*)(ob + 12 * MB);

  dim3 blk(256);
  dim3 gP(DIN / 128, MROWS / 128);      // N=1024 MFMA
  dim3 gM(DM / 128, MROWS / 128);       // N=512 MFMA
  dim3 gF(DFF / 128, MROWS / 128);      // N=2048 MFMA
  dim3 gC(DIN / 64, MROWS / 64);        // convT tiles
  dim3 gX(MROWS / BN, 64 / BM);         // xdblT: M=64
  dim3 gD(MROWS / BN, DIN / BM);        // dtT: M=1024

  // ---- weight conversions into d_out ----
  cvt_k<<<(2 * DIN * DM) / 256, blk, 0, stream>>>(in1_w, in1b, 2 * DIN * DM);
  cvt_k<<<(2 * DIN * DM) / 256, blk, 0, stream>>>(in2_w, in2b, 2 * DIN * DM);
  cvt_k<<<(DM * DIN) / 256, blk, 0, stream>>>(outp1_w, o1b, DM * DIN);
  cvt_k<<<(DM * DIN) / 256, blk, 0, stream>>>(outp2_w, o2b, DM * DIN);
  cvt_k<<<(DFF * DM) / 256, blk, 0, stream>>>(c1_w, c1b, DFF * DM);
  cvt_k<<<(DM * DFF) / 256, blk, 0, stream>>>(c2_w, c2b, DM * DFF);

  // ---- direction 1 prelude ----
  mgemm_k<MEPI_STORE_BF16, false, float, bf16><<<gP, blk, 0, stream>>>(
      x, DM, in1b, DM, A, DIN, nullptr, nullptr, DM);                    // xs1
  convT_k<<<gC, blk, 0, stream>>>(A, conv1_w, conv1_b, B);               // xcT1
  gemmBT_k<EPI_NONE, bf16, float><<<gX, blk, 0, stream>>>(
      xp1_w, B, xdT1, MROWS, nullptr, DIN);                              // xdblT1
  gemmBT_k<EPI_SOFTPLUS_ROW, float, bf16><<<gD, blk, 0, stream>>>(
      dtp1_w, xdT1, C, MROWS, dtp1_b, DTRANK);                           // dtT1

  // ---- direction 2 prelude ----
  mgemm_k<MEPI_STORE_BF16, true, float, bf16><<<gP, blk, 0, stream>>>(
      x, DM, in2b, DM, D, DIN, nullptr, nullptr, DM);                    // xs2
  convT_k<<<gC, blk, 0, stream>>>(D, conv2_w, conv2_b, E);               // xcT2
  gemmBT_k<EPI_NONE, bf16, float><<<gX, blk, 0, stream>>>(
      xp2_w, E, xdT2, MROWS, nullptr, DIN);                              // xdblT2
  gemmBT_k<EPI_SOFTPLUS_ROW, float, bf16><<<gD, blk, 0, stream>>>(
      dtp2_w, xdT2, F, MROWS, dtp2_b, DTRANK);                           // dtT2

  // ---- merged bidirectional scan: y1 -> A, y2 -> D ----
  scan_k<<<2 * B_SZ * (DIN / 16), blk, 0, stream>>>(
      (const u16*)C, (const u16*)F, (const u16*)B, (const u16*)E,
      xdT1, xdT2, Alog1, Alog2, D1, D2, A, D);

  // ---- gates (in-place over y) ----
  mgemm_k<MEPI_GATE, false, float, bf16><<<gP, blk, 0, stream>>>(
      x, DM, in1b + (long)DIN * DM, DM, A, DIN, nullptr, nullptr, DM);
  mgemm_k<MEPI_GATE, true, float, bf16><<<gP, blk, 0, stream>>>(
      x, DM, in2b + (long)DIN * DM, DM, D, DIN, nullptr, nullptr, DM);

  // ---- merge: newx = y1@W1^T + flip(y2)@W2^T + x -> C (fp32) ----
  mmerge_k<<<gM, blk, 0, stream>>>(A, D, o1b, o2b, x, Cf);

  // ---- LN1: fp32 -> B, bf16 -> E ----
  ln_k<<<MROWS, blk, 0, stream>>>(Cf, ln1_g, ln1_b, Bf, E);

  // ---- FFN (single up, single down) ----
  mgemm_k<MEPI_BIAS_GELU, false, bf16, bf16><<<gF, blk, 0, stream>>>(
      E, DM, c1b, DM, ffn, DFF, c1_b, nullptr, DM);
  mgemm_k<MEPI_BIAS_RES, false, bf16, float><<<gM, blk, 0, stream>>>(
      ffn, DFF, c2b, DFF, Af, DM, c2_b, Bf, DFF);

  // ---- LN2 -> d_out (weights/xdblT scratch dead) ----
  ln_k<<<MROWS, blk, 0, stream>>>(Af, ln2_g, ln2_b, (float*)d_out, nullptr);
}